// Round 14
// baseline (799.160 us; speedup 1.0000x reference)
//
#include <hip/hip_runtime.h>
#include <hip/hip_bf16.h>

typedef __attribute__((ext_vector_type(8))) short    bf16x8;
typedef __attribute__((ext_vector_type(4))) float    f32x4;
typedef __attribute__((ext_vector_type(4))) unsigned u32x4;

#define MTPW 4   // tiles per wave in msg_kernel
#define LOG2E  1.442695041f
#define LOG2E2 2.885390082f
#define MFMA __builtin_amdgcn_mfma_f32_16x16x32_bf16

__device__ __forceinline__ float rcp_(float v){ return __builtin_amdgcn_rcpf(v); }
__device__ __forceinline__ float exp2_(float v){ return __builtin_amdgcn_exp2f(v); }
__device__ __forceinline__ unsigned pk2(float lo, float hi){
    __hip_bfloat162 h = __float22bfloat162_rn(float2{lo, hi});
    return *(unsigned*)&h;
}
__device__ __forceinline__ float lo2f(unsigned u){ return __uint_as_float(u << 16); }
__device__ __forceinline__ float hi2f(unsigned u){ return __uint_as_float(u & 0xFFFF0000u); }

union U4 { bf16x8 v; unsigned u[4]; };

// identity-order 8-column loader
__device__ __forceinline__ bf16x8 ldw8(const float* __restrict__ p){
    const float4 a = *(const float4*)p;
    const float4 b = *(const float4*)(p + 4);
    U4 r;
    r.u[0] = pk2(a.x, a.y); r.u[1] = pk2(a.z, a.w);
    r.u[2] = pk2(b.x, b.y); r.u[3] = pk2(b.z, b.w);
    return r.v;
}
// sigma-permuted loader: slot 8q+j <- column {4q+j (j<4) | 16+4q+j-4}
__device__ __forceinline__ bf16x8 ldw8p(const float* __restrict__ rowp, int lq){
    const float4 a = *(const float4*)(rowp + 4*lq);
    const float4 b = *(const float4*)(rowp + 16 + 4*lq);
    U4 r;
    r.u[0] = pk2(a.x, a.y); r.u[1] = pk2(a.z, a.w);
    r.u[2] = pk2(b.x, b.y); r.u[3] = pk2(b.z, b.w);
    return r.v;
}

// 8 x ds_read_b128 + single waitcnt; volatile so reads re-issue per step
#define LDS_RD8(AD,d0,d1,d2,d3,d4,d5,d6,d7,O0,O1,O2,O3,O4,O5,O6,O7)         \
  asm volatile("ds_read_b128 %0, %8 offset:" O0 "\n\t"                      \
               "ds_read_b128 %1, %8 offset:" O1 "\n\t"                      \
               "ds_read_b128 %2, %8 offset:" O2 "\n\t"                      \
               "ds_read_b128 %3, %8 offset:" O3 "\n\t"                      \
               "ds_read_b128 %4, %8 offset:" O4 "\n\t"                      \
               "ds_read_b128 %5, %8 offset:" O5 "\n\t"                      \
               "ds_read_b128 %6, %8 offset:" O6 "\n\t"                      \
               "ds_read_b128 %7, %8 offset:" O7 "\n\t"                      \
               "s_waitcnt lgkmcnt(0)"                                       \
               : "=&v"(d0),"=&v"(d1),"=&v"(d2),"=&v"(d3),                   \
                 "=&v"(d4),"=&v"(d5),"=&v"(d6),"=&v"(d7)                    \
               : "v"(AD))

__device__ __forceinline__ bf16x8 bc8(u32x4 x){ return __builtin_bit_cast(bf16x8, x); }

// merged-rcp gate updates; Ea=e^-i, Ef=e^-f, Eg=e^2g, Eo=e^-o (scales in weights)
__device__ __forceinline__ void gates4_first(const f32x4 ai, const f32x4 ag, const f32x4 ao,
                                             float c[4], float h[4]){
#pragma unroll
    for (int r = 0; r < 4; ++r) {
        const float Ea = exp2_(ai[r]);
        const float Eg = exp2_(ag[r]);
        const float Eo = exp2_(ao[r]);
        c[r] = (Eg - 1.f) * rcp_((Ea + 1.f) * (Eg + 1.f));
        const float Ec = exp2_(LOG2E2 * c[r]);
        h[r] = (Ec - 1.f) * rcp_((Eo + 1.f) * (Ec + 1.f));
    }
}
__device__ __forceinline__ void gates4_mid(const f32x4 ai, const f32x4 af,
                                           const f32x4 ag, const f32x4 ao,
                                           float c[4], float h[4]){
#pragma unroll
    for (int r = 0; r < 4; ++r) {
        const float Ea = exp2_(ai[r]);
        const float Ef = exp2_(af[r]);
        const float Eg = exp2_(ag[r]);
        const float Eo = exp2_(ao[r]);
        const float p  = (Ea + 1.f) * (Eg + 1.f);
        const float f1 = Ef + 1.f;
        const float num = fmaf(c[r], p, (Eg - 1.f) * f1);
        c[r] = num * rcp_(p * f1);
        const float Ec = exp2_(LOG2E2 * c[r]);
        h[r] = (Ec - 1.f) * rcp_((Eo + 1.f) * (Ec + 1.f));
    }
}
__device__ __forceinline__ void gates4_last(const f32x4 ai, const f32x4 af,
                                            const f32x4 ag, float c[4]){
#pragma unroll
    for (int r = 0; r < 4; ++r) {
        const float Ea = exp2_(ai[r]);
        const float Ef = exp2_(af[r]);
        const float Eg = exp2_(ag[r]);
        const float p  = (Ea + 1.f) * (Eg + 1.f);
        const float f1 = Ef + 1.f;
        const float num = fmaf(c[r], p, (Eg - 1.f) * f1);
        c[r] = num * rcp_(p * f1);
    }
}

// ---------------- kernel 1: coor = relu(x@W1^T)@W2^T -> bf16 [N,32] ----------------
__global__ __launch_bounds__(256) void coor_kernel(
    const float* __restrict__ x, const float* __restrict__ w1,
    const float* __restrict__ w2, unsigned short* __restrict__ coorb, int N)
{
    __shared__ float sW1[96];
    __shared__ float sW2[1024];
    const int tid = threadIdx.x;
    if (tid < 96) sW1[tid] = w1[tid];
    for (int i = tid; i < 1024; i += 256) sW2[i] = w2[i];
    __syncthreads();
    int n = blockIdx.x * 256 + tid;
    if (n >= N) return;
    const float x0 = x[n*3+0], x1 = x[n*3+1], x2 = x[n*3+2];
    float h[32];
#pragma unroll
    for (int k = 0; k < 32; ++k)
        h[k] = fmaxf(sW1[k*3+0]*x0 + sW1[k*3+1]*x1 + sW1[k*3+2]*x2, 0.0f);
    union { uint4 q[4]; unsigned u[16]; } st;
#pragma unroll
    for (int p = 0; p < 16; ++p) {
        float a0 = 0.f, a1 = 0.f;
#pragma unroll
        for (int k = 0; k < 32; ++k) {
            a0 += sW2[(2*p)  *32 + k] * h[k];
            a1 += sW2[(2*p+1)*32 + k] * h[k];
        }
        st.u[p] = pk2(a0, a1);
    }
    uint4* cp = (uint4*)(coorb + (size_t)n * 32);
#pragma unroll
    for (int w = 0; w < 4; ++w) cp[w] = st.q[w];
}

// ---------------- kernel 2: one-direction LSTM, 1 tile/wave, weights in LDS ----------------
// (r11 proven-best config: per-step x load, no fusion, launch_bounds(256,4))
template<int DIR>
__global__ __launch_bounds__(256, 4) void lstm_kernel(
    const float* __restrict__ edge_traj,
    const float* __restrict__ w_ih, const float* __restrict__ w_hh,
    const float* __restrict__ b_ih, const float* __restrict__ b_hh,
    unsigned* __restrict__ cbuf, int E)
{
    __shared__ unsigned lds_w[4096];
    const int tid = threadIdx.x;
    for (int i = tid; i < 512; i += 256) {
        const int m = i >> 6, ln = i & 63;
        const int le2 = ln & 15, lq2 = ln >> 4;
        const int row = 16*m + le2;
        const float s = (m == 4 || m == 5) ? LOG2E2 : -LOG2E;
        const float4 a = *(const float4*)(w_hh + row*32 + 4*lq2);
        const float4 b = *(const float4*)(w_hh + row*32 + 16 + 4*lq2);
        unsigned* wp = &lds_w[(size_t)i * 4];
        wp[0] = pk2(a.x*s, a.y*s); wp[1] = pk2(a.z*s, a.w*s);
        wp[2] = pk2(b.x*s, b.y*s); wp[3] = pk2(b.z*s, b.w*s);
        unsigned* xp = &lds_w[(size_t)(512 + i) * 4];
        if (lq2 == 0) {
            const float* p = w_ih + row * 6;
            xp[0] = pk2(p[0]*s, p[1]*s);
            xp[1] = pk2(p[2]*s, p[3]*s);
            xp[2] = pk2(p[4]*s, p[5]*s);
            xp[3] = pk2((b_ih[row] + b_hh[row])*s, 0.f);
        } else {
            xp[0] = 0u; xp[1] = 0u; xp[2] = 0u; xp[3] = 0u;
        }
    }
    __syncthreads();

    const int lane = tid & 63;
    const int wid  = tid >> 6;
    const int le   = lane & 15;
    const int lq   = lane >> 4;
    const bool l0  = (lq == 0);
    const unsigned lds_addr = (unsigned)(size_t)lds_w + (unsigned)lane * 16u;
    const f32x4 Z4 = {0.f, 0.f, 0.f, 0.f};

    const long tile = (long)blockIdx.x * 4 + wid;
    const long e0 = tile * 16;
    if (e0 >= E) return;
    const long er = e0 + le;
    const bool valid = er < E;
    const float* xb = edge_traj + (valid ? er : (E - 1)) * 48;

    U4 hf; hf.u[0]=hf.u[1]=hf.u[2]=hf.u[3]=0u;
    float cl[4]={0,0,0,0}, ch[4]={0,0,0,0};

#pragma unroll
    for (int t = 0; t < 8; ++t) {
        const int te = DIR ? (7 - t) : t;
        U4 xf;
        {
            const float* xp = xb + te * 6;
            const float2 a  = *(const float2*)xp;
            const float2 b2 = *(const float2*)(xp + 2);
            const float2 c2 = *(const float2*)(xp + 4);
            xf.u[0] = l0 ? pk2(a.x, a.y)   : 0u;
            xf.u[1] = l0 ? pk2(b2.x, b2.y) : 0u;
            xf.u[2] = l0 ? pk2(c2.x, c2.y) : 0u;
            xf.u[3] = l0 ? 0x3f80u         : 0u;
        }

        // ---- lo m-group {0,2,4,6}
        u32x4 f0,f1,f2,f3,f4,f5,f6,f7;
        LDS_RD8(lds_addr, f0,f1,f2,f3,f4,f5,f6,f7,
                "0","2048","4096","6144","8192","10240","12288","14336");
        f32x4 ai = MFMA(bc8(f4), xf.v, Z4, 0,0,0);
        f32x4 af = Z4, ao = Z4;
        if (t != 0) af = MFMA(bc8(f5), xf.v, Z4, 0,0,0);
        f32x4 ag = MFMA(bc8(f6), xf.v, Z4, 0,0,0);
        if (t != 7) ao = MFMA(bc8(f7), xf.v, Z4, 0,0,0);
        if (t > 0) {
            ai = MFMA(bc8(f0), hf.v, ai, 0,0,0);
            af = MFMA(bc8(f1), hf.v, af, 0,0,0);
            ag = MFMA(bc8(f2), hf.v, ag, 0,0,0);
            if (t != 7) ao = MFMA(bc8(f3), hf.v, ao, 0,0,0);
        }
        u32x4 g0,g1,g2,g3,g4,g5,g6,g7;
        LDS_RD8(lds_addr, g0,g1,g2,g3,g4,g5,g6,g7,
                "1024","3072","5120","7168","9216","11264","13312","15360");

        float hl[4], hh[4];
        if (t == 0)      gates4_first(ai, ag, ao, cl, hl);
        else if (t == 7) gates4_last(ai, af, ag, cl);
        else             gates4_mid(ai, af, ag, ao, cl, hl);

        f32x4 bi = MFMA(bc8(g4), xf.v, Z4, 0,0,0);
        f32x4 bf = Z4, bo = Z4;
        if (t != 0) bf = MFMA(bc8(g5), xf.v, Z4, 0,0,0);
        f32x4 bg = MFMA(bc8(g6), xf.v, Z4, 0,0,0);
        if (t != 7) bo = MFMA(bc8(g7), xf.v, Z4, 0,0,0);
        if (t > 0) {
            bi = MFMA(bc8(g0), hf.v, bi, 0,0,0);
            bf = MFMA(bc8(g1), hf.v, bf, 0,0,0);
            bg = MFMA(bc8(g2), hf.v, bg, 0,0,0);
            if (t != 7) bo = MFMA(bc8(g3), hf.v, bo, 0,0,0);
        }
        if (t == 0)      gates4_first(bi, bg, bo, ch, hh);
        else if (t == 7) gates4_last(bi, bf, bg, ch);
        else             gates4_mid(bi, bf, bg, bo, ch, hh);

        if (t < 7) {
            hf.u[0] = pk2(hl[0], hl[1]); hf.u[1] = pk2(hl[2], hl[3]);
            hf.u[2] = pk2(hh[0], hh[1]); hf.u[3] = pk2(hh[2], hh[3]);
        }
    }

    // c -> sigma-layout e-major bf16
    if (valid) {
        U4 cw;
        cw.u[0] = pk2(cl[0], cl[1]);
        cw.u[1] = pk2(cl[2], cl[3]);
        cw.u[2] = pk2(ch[0], ch[1]);
        cw.u[3] = pk2(ch[2], ch[3]);
        unsigned* dp = cbuf + er * 16 + lq * 4;
        if (DIR == 0) {
            *(uint4*)dp = *(uint4*)cw.u;
        } else {
            const uint4 f = *(const uint4*)dp;
            uint4 o;
            o.x = pk2(0.5f*(lo2f(f.x)+lo2f(cw.u[0])), 0.5f*(hi2f(f.x)+hi2f(cw.u[0])));
            o.y = pk2(0.5f*(lo2f(f.y)+lo2f(cw.u[1])), 0.5f*(hi2f(f.y)+hi2f(cw.u[1])));
            o.z = pk2(0.5f*(lo2f(f.z)+lo2f(cw.u[2])), 0.5f*(hi2f(f.z)+hi2f(cw.u[2])));
            o.w = pk2(0.5f*(lo2f(f.w)+lo2f(cw.u[3])), 0.5f*(hi2f(f.w)+hi2f(cw.u[3])));
            *(uint4*)dp = o;
        }
    }
}

// ---------------- kernel 3: message MLP, writes msg bf16 IN PLACE over tr rows ----------------
__global__ __launch_bounds__(256, 4) void msg_kernel(
    unsigned* trmsg,
    const float* __restrict__ nn2_w1, const float* __restrict__ nn2_w2,
    const int* __restrict__ edge_index,
    const unsigned short* __restrict__ coorb, int E)
{
    const int lane = threadIdx.x & 63;
    const int wid  = threadIdx.x >> 6;
    const int le   = lane & 15;
    const int lq   = lane >> 4;
    const f32x4 Z4 = {0.f, 0.f, 0.f, 0.f};

    bf16x8 w1a[2][3], w2a[2];
#pragma unroll
    for (int mm = 0; mm < 2; ++mm) {
        const int row = 16*mm + le;
        w1a[mm][0] = ldw8(nn2_w1 + row*96 +  8*lq);
        w1a[mm][1] = ldw8(nn2_w1 + row*96 + 32 + 8*lq);
        w1a[mm][2] = ldw8p(nn2_w1 + row*96 + 64, lq);
        w2a[mm]    = ldw8p(nn2_w2 + row*32, lq);
    }

    const long gw = (long)blockIdx.x * 4 + wid;
    for (int it = 0; it < MTPW; ++it) {
        const long tile = gw * MTPW + it;
        const long e0 = tile * 16;
        if (e0 >= E) break;
        const long e_raw = e0 + le;
        const bool valid = e_raw < E;
        const long ec = valid ? e_raw : (E - 1);

        U4 tf;
        if (valid) *(uint4*)tf.u = *(const uint4*)(trmsg + e_raw * 16 + lq * 4);
        else tf.u[0] = tf.u[1] = tf.u[2] = tf.u[3] = 0u;

        const int src = edge_index[ec];
        const int dst = edge_index[E + ec];
        U4 df, sf;
        {
            const uint4 dv = *(const uint4*)(coorb + (size_t)dst*32 + lq*8);
            const uint4 sv = *(const uint4*)(coorb + (size_t)src*32 + lq*8);
            df.u[0]=dv.x; df.u[1]=dv.y; df.u[2]=dv.z; df.u[3]=dv.w;
            sf.u[0]=sv.x; sf.u[1]=sv.y; sf.u[2]=sv.z; sf.u[3]=sv.w;
        }

        f32x4 h1[2];
#pragma unroll
        for (int mm = 0; mm < 2; ++mm) {
            f32x4 a = MFMA(w1a[mm][0], df.v, Z4, 0,0,0);
            a = MFMA(w1a[mm][1], sf.v, a, 0,0,0);
            a = MFMA(w1a[mm][2], tf.v, a, 0,0,0);
            h1[mm] = a;
        }
        U4 gf;
        gf.u[0] = pk2(fmaxf(h1[0][0],0.f), fmaxf(h1[0][1],0.f));
        gf.u[1] = pk2(fmaxf(h1[0][2],0.f), fmaxf(h1[0][3],0.f));
        gf.u[2] = pk2(fmaxf(h1[1][0],0.f), fmaxf(h1[1][1],0.f));
        gf.u[3] = pk2(fmaxf(h1[1][2],0.f), fmaxf(h1[1][3],0.f));

        const f32x4 o0 = MFMA(w2a[0], gf.v, Z4, 0,0,0);
        const f32x4 o1 = MFMA(w2a[1], gf.v, Z4, 0,0,0);
        if (valid) {
            U4 cw;
            cw.u[0] = pk2(o0[0], o0[1]);
            cw.u[1] = pk2(o0[2], o0[3]);
            cw.u[2] = pk2(o1[0], o1[1]);
            cw.u[3] = pk2(o1[2], o1[3]);
            *(uint4*)(trmsg + e_raw * 16 + lq * 4) = *(uint4*)cw.u;
        }
    }
}

// ---------------- CSR build ----------------
__global__ __launch_bounds__(256) void hist_kernel(
    const int* __restrict__ ei, int* __restrict__ cnt, int E)
{
    const int e = blockIdx.x*256 + threadIdx.x;
    if (e < E) atomicAdd(&cnt[ei[E + e]], 1);
}

__global__ __launch_bounds__(256) void scan1_kernel(
    const int* __restrict__ cnt, int* __restrict__ bsum, int N)
{
    __shared__ int sp[4];
    const int tid = threadIdx.x;
    const int n = blockIdx.x*256 + tid;
    int c = (n < N) ? cnt[n] : 0;
#pragma unroll
    for (int m = 1; m < 64; m <<= 1) c += __shfl_xor(c, m, 64);
    if ((tid & 63) == 0) sp[tid >> 6] = c;
    __syncthreads();
    if (tid == 0) bsum[blockIdx.x] = sp[0] + sp[1] + sp[2] + sp[3];
}

__global__ __launch_bounds__(512) void scan2_kernel(
    int* __restrict__ bsum, int* __restrict__ offs, int nblk, int E, int N)
{
    __shared__ int s[512];
    const int tid = threadIdx.x;
    const int v = (tid < nblk) ? bsum[tid] : 0;
    s[tid] = v;
    __syncthreads();
    for (int off = 1; off < 512; off <<= 1) {
        const int t = (tid >= off) ? s[tid - off] : 0;
        __syncthreads();
        s[tid] += t;
        __syncthreads();
    }
    if (tid < nblk) bsum[tid] = s[tid] - v;
    if (tid == 0) offs[N] = E;
}

__global__ __launch_bounds__(256) void scan3_kernel(
    const int* __restrict__ cnt, const int* __restrict__ bsum,
    int* __restrict__ offs, int* __restrict__ cursor, int N)
{
    __shared__ int s[256];
    const int tid = threadIdx.x;
    const int n = blockIdx.x*256 + tid;
    const int v = (n < N) ? cnt[n] : 0;
    s[tid] = v;
    __syncthreads();
    for (int off = 1; off < 256; off <<= 1) {
        const int t = (tid >= off) ? s[tid - off] : 0;
        __syncthreads();
        s[tid] += t;
        __syncthreads();
    }
    if (n < N) {
        const int o = bsum[blockIdx.x] + s[tid] - v;
        offs[n] = o;
        cursor[n] = o;
    }
}

__global__ __launch_bounds__(256) void fill_kernel(
    const int* __restrict__ ei, int* __restrict__ cursor,
    int* __restrict__ eidx, int E)
{
    const int e = blockIdx.x*256 + threadIdx.x;
    if (e < E) {
        const int p = atomicAdd(&cursor[ei[E + e]], 1);
        eidx[p] = e;
    }
}

// ---------------- fused gather+agg: partials[b][jj] = sum_{n in block} relu(agg[n]@W1^T)[jj] ----------------
// 16 lane-groups per block, one node each: gather incoming msg rows (coalesced 64B),
// LDS-stage the 32-vector, each lane computes rows jj=2le,2le+1, then block-reduce.
// aggv round-trip eliminated.
__global__ __launch_bounds__(256) void gather_agg_kernel(
    const unsigned* __restrict__ msg, const int* __restrict__ offs,
    const int* __restrict__ eidx, const float* __restrict__ nn_w1,
    float* __restrict__ partials, int N)
{
    __shared__ float sW[1024];      // sigma-permuted columns of nn_w1
    __shared__ float sA[16][33];    // per-group agg row (sigma-slot order)
    __shared__ float sP[4][32];
    const int tid = threadIdx.x;
    for (int i = tid; i < 1024; i += 256) {
        const int jj = i >> 5, s = i & 31, q = s >> 3, j = s & 7;
        const int col = (j < 4) ? (4*q + j) : (16 + 4*q + (j - 4));
        sW[i] = nn_w1[jj*32 + col];
    }
    const int lane = tid & 63;
    const int wid  = tid >> 6;
    const int g    = lane >> 4;
    const int grp  = wid*4 + g;           // 0..15
    const int le   = lane & 15;
    const int n = blockIdx.x*16 + grp;
    float sx = 0.f, sy = 0.f;
    if (n < N) {
        const int beg = offs[n], end = offs[n+1];
        for (int i = beg; i < end; ++i) {
            const unsigned w = msg[(size_t)eidx[i]*16 + le];
            sx += lo2f(w); sy += hi2f(w);
        }
    }
    sA[grp][2*le]   = sx;
    sA[grp][2*le+1] = sy;
    __syncthreads();
    float h0 = 0.f, h1 = 0.f;
#pragma unroll
    for (int k = 0; k < 32; ++k) {
        const float a = sA[grp][k];
        h0 = fmaf(sW[(2*le)*32 + k],   a, h0);
        h1 = fmaf(sW[(2*le+1)*32 + k], a, h1);
    }
    h0 = fmaxf(h0, 0.f);
    h1 = fmaxf(h1, 0.f);
    // reduce the 4 groups within the wave (lanes with equal le)
    h0 += __shfl_xor(h0, 16, 64);  h1 += __shfl_xor(h1, 16, 64);
    h0 += __shfl_xor(h0, 32, 64);  h1 += __shfl_xor(h1, 32, 64);
    if (lane < 16) { sP[wid][2*le] = h0; sP[wid][2*le+1] = h1; }
    __syncthreads();
    if (tid < 32)
        partials[(size_t)blockIdx.x*32 + tid]
            = sP[0][tid] + sP[1][tid] + sP[2][tid] + sP[3][tid];
}

// ---------------- final: s32 = sum(partials); out = nn_w2 @ s32 ----------------
__global__ __launch_bounds__(256) void reduce_kernel(
    const float* __restrict__ partials, const float* __restrict__ nn_w2,
    float* __restrict__ out, int nblk)
{
    __shared__ float sR[8][32];
    __shared__ float sS[32];
    const int tid = threadIdx.x;
    const int col = tid & 31;
    const int row = tid >> 5;
    float s = 0.f;
    for (int i = row; i < nblk; i += 8) s += partials[(size_t)i*32 + col];
    sR[row][col] = s;
    __syncthreads();
    if (row == 0) {
        float t = 0.f;
#pragma unroll
        for (int r = 0; r < 8; ++r) t += sR[r][col];
        sS[col] = t;
    }
    __syncthreads();
    if (tid < 64) {
        float acc = 0.f;
#pragma unroll
        for (int k = 0; k < 32; ++k) acc += nn_w2[tid*32+k] * sS[k];
        out[tid] = acc;
    }
}

extern "C" void kernel_launch(void* const* d_in, const int* in_sizes, int n_in,
                              void* d_out, int out_size, void* d_ws, size_t ws_size,
                              hipStream_t stream)
{
    const float* x         = (const float*)d_in[0];
    const float* edge_traj = (const float*)d_in[1];
    const float* w_ih_f    = (const float*)d_in[2];
    const float* w_hh_f    = (const float*)d_in[3];
    const float* b_ih_f    = (const float*)d_in[4];
    const float* b_hh_f    = (const float*)d_in[5];
    const float* w_ih_b    = (const float*)d_in[6];
    const float* w_hh_b    = (const float*)d_in[7];
    const float* b_ih_b    = (const float*)d_in[8];
    const float* b_hh_b    = (const float*)d_in[9];
    const float* coor_w1   = (const float*)d_in[10];
    const float* coor_w2   = (const float*)d_in[11];
    const float* nn2_w1    = (const float*)d_in[12];
    const float* nn2_w2    = (const float*)d_in[13];
    const float* nn_w1     = (const float*)d_in[14];
    const float* nn_w2     = (const float*)d_in[15];
    const int* edge_index  = (const int*)d_in[16];
    const int N = in_sizes[0] / 3;
    const int E = in_sizes[16] / 2;
    const int nblk = (N + 255) / 256;   // 256-thread node blocks (scans)
    const int gblk = (N + 15) / 16;     // gather_agg blocks

    float* partials = (float*)d_ws;                               // gblk*32 f32
    unsigned short* coorb = (unsigned short*)(partials + (size_t)gblk * 32); // N*32 bf16
    unsigned* cbuf = (unsigned*)(coorb + (size_t)N * 32);         // E*16 u32 (tr -> msg)
    int* cnt    = (int*)(cbuf + (size_t)E * 16);                  // N
    int* offs   = cnt + N;                                        // N+1
    int* cursor = offs + N + 1;                                   // N
    int* eidx   = cursor + N;                                     // E
    int* bsum   = eidx + E;                                       // nblk

    (void)hipMemsetAsync(cnt, 0, (size_t)N * sizeof(int), stream);

    coor_kernel<<<nblk, 256, 0, stream>>>(x, coor_w1, coor_w2, coorb, N);

    const long tiles   = ((long)E + 15) / 16;
    const int  lblocks = (int)((tiles + 3) / 4);
    lstm_kernel<0><<<lblocks, 256, 0, stream>>>(edge_traj,
        w_ih_f, w_hh_f, b_ih_f, b_hh_f, cbuf, E);
    lstm_kernel<1><<<lblocks, 256, 0, stream>>>(edge_traj,
        w_ih_b, w_hh_b, b_ih_b, b_hh_b, cbuf, E);

    const int eblk = (E + 255) / 256;
    hist_kernel<<<eblk, 256, 0, stream>>>(edge_index, cnt, E);
    scan1_kernel<<<nblk, 256, 0, stream>>>(cnt, bsum, N);
    scan2_kernel<<<1, 512, 0, stream>>>(bsum, offs, nblk, E, N);
    scan3_kernel<<<nblk, 256, 0, stream>>>(cnt, bsum, offs, cursor, N);
    fill_kernel<<<eblk, 256, 0, stream>>>(edge_index, cursor, eidx, E);

    const int mblocks = (int)((tiles + 4*MTPW - 1) / (4*MTPW));
    msg_kernel<<<mblocks, 256, 0, stream>>>(cbuf, nn2_w1, nn2_w2,
        edge_index, coorb, E);

    gather_agg_kernel<<<gblk, 256, 0, stream>>>(cbuf, offs, eidx, nn_w1,
        partials, N);
    reduce_kernel<<<1, 256, 0, stream>>>(partials, nn_w2, (float*)d_out, gblk);
}

// Round 15
// 607.328 us; speedup vs baseline: 1.3159x; 1.3159x over previous
//
#include <hip/hip_runtime.h>
#include <hip/hip_bf16.h>

typedef __attribute__((ext_vector_type(8))) short    bf16x8;
typedef __attribute__((ext_vector_type(4))) float    f32x4;
typedef __attribute__((ext_vector_type(4))) unsigned u32x4;

#define MTPW 4   // tiles per wave in msg_kernel
#define LOG2E  1.442695041f
#define LOG2E2 2.885390082f
#define MFMA __builtin_amdgcn_mfma_f32_16x16x32_bf16

__device__ __forceinline__ float rcp_(float v){ return __builtin_amdgcn_rcpf(v); }
__device__ __forceinline__ float exp2_(float v){ return __builtin_amdgcn_exp2f(v); }
__device__ __forceinline__ unsigned pk2(float lo, float hi){
    __hip_bfloat162 h = __float22bfloat162_rn(float2{lo, hi});
    return *(unsigned*)&h;
}
__device__ __forceinline__ float lo2f(unsigned u){ return __uint_as_float(u << 16); }
__device__ __forceinline__ float hi2f(unsigned u){ return __uint_as_float(u & 0xFFFF0000u); }

union U4 { bf16x8 v; unsigned u[4]; };

// identity-order 8-column loader
__device__ __forceinline__ bf16x8 ldw8(const float* __restrict__ p){
    const float4 a = *(const float4*)p;
    const float4 b = *(const float4*)(p + 4);
    U4 r;
    r.u[0] = pk2(a.x, a.y); r.u[1] = pk2(a.z, a.w);
    r.u[2] = pk2(b.x, b.y); r.u[3] = pk2(b.z, b.w);
    return r.v;
}
// sigma-permuted loader: slot 8q+j <- column {4q+j (j<4) | 16+4q+j-4}
__device__ __forceinline__ bf16x8 ldw8p(const float* __restrict__ rowp, int lq){
    const float4 a = *(const float4*)(rowp + 4*lq);
    const float4 b = *(const float4*)(rowp + 16 + 4*lq);
    U4 r;
    r.u[0] = pk2(a.x, a.y); r.u[1] = pk2(a.z, a.w);
    r.u[2] = pk2(b.x, b.y); r.u[3] = pk2(b.z, b.w);
    return r.v;
}

// 8 x ds_read_b128 + single waitcnt; volatile so reads re-issue per step
#define LDS_RD8(AD,d0,d1,d2,d3,d4,d5,d6,d7,O0,O1,O2,O3,O4,O5,O6,O7)         \
  asm volatile("ds_read_b128 %0, %8 offset:" O0 "\n\t"                      \
               "ds_read_b128 %1, %8 offset:" O1 "\n\t"                      \
               "ds_read_b128 %2, %8 offset:" O2 "\n\t"                      \
               "ds_read_b128 %3, %8 offset:" O3 "\n\t"                      \
               "ds_read_b128 %4, %8 offset:" O4 "\n\t"                      \
               "ds_read_b128 %5, %8 offset:" O5 "\n\t"                      \
               "ds_read_b128 %6, %8 offset:" O6 "\n\t"                      \
               "ds_read_b128 %7, %8 offset:" O7 "\n\t"                      \
               "s_waitcnt lgkmcnt(0)"                                       \
               : "=&v"(d0),"=&v"(d1),"=&v"(d2),"=&v"(d3),                   \
                 "=&v"(d4),"=&v"(d5),"=&v"(d6),"=&v"(d7)                    \
               : "v"(AD))

__device__ __forceinline__ bf16x8 bc8(u32x4 x){ return __builtin_bit_cast(bf16x8, x); }

// merged-rcp gate updates; Ea=e^-i, Ef=e^-f, Eg=e^2g, Eo=e^-o (scales in weights)
__device__ __forceinline__ void gates4_first(const f32x4 ai, const f32x4 ag, const f32x4 ao,
                                             float c[4], float h[4]){
#pragma unroll
    for (int r = 0; r < 4; ++r) {
        const float Ea = exp2_(ai[r]);
        const float Eg = exp2_(ag[r]);
        const float Eo = exp2_(ao[r]);
        c[r] = (Eg - 1.f) * rcp_((Ea + 1.f) * (Eg + 1.f));
        const float Ec = exp2_(LOG2E2 * c[r]);
        h[r] = (Ec - 1.f) * rcp_((Eo + 1.f) * (Ec + 1.f));
    }
}
__device__ __forceinline__ void gates4_mid(const f32x4 ai, const f32x4 af,
                                           const f32x4 ag, const f32x4 ao,
                                           float c[4], float h[4]){
#pragma unroll
    for (int r = 0; r < 4; ++r) {
        const float Ea = exp2_(ai[r]);
        const float Ef = exp2_(af[r]);
        const float Eg = exp2_(ag[r]);
        const float Eo = exp2_(ao[r]);
        const float p  = (Ea + 1.f) * (Eg + 1.f);
        const float f1 = Ef + 1.f;
        const float num = fmaf(c[r], p, (Eg - 1.f) * f1);
        c[r] = num * rcp_(p * f1);
        const float Ec = exp2_(LOG2E2 * c[r]);
        h[r] = (Ec - 1.f) * rcp_((Eo + 1.f) * (Ec + 1.f));
    }
}
__device__ __forceinline__ void gates4_last(const f32x4 ai, const f32x4 af,
                                            const f32x4 ag, float c[4]){
#pragma unroll
    for (int r = 0; r < 4; ++r) {
        const float Ea = exp2_(ai[r]);
        const float Ef = exp2_(af[r]);
        const float Eg = exp2_(ag[r]);
        const float p  = (Ea + 1.f) * (Eg + 1.f);
        const float f1 = Ef + 1.f;
        const float num = fmaf(c[r], p, (Eg - 1.f) * f1);
        c[r] = num * rcp_(p * f1);
    }
}

// ---------------- kernel 1: coor = relu(x@W1^T)@W2^T -> bf16 [N,32] ----------------
__global__ __launch_bounds__(256) void coor_kernel(
    const float* __restrict__ x, const float* __restrict__ w1,
    const float* __restrict__ w2, unsigned short* __restrict__ coorb, int N)
{
    __shared__ float sW1[96];
    __shared__ float sW2[1024];
    const int tid = threadIdx.x;
    if (tid < 96) sW1[tid] = w1[tid];
    for (int i = tid; i < 1024; i += 256) sW2[i] = w2[i];
    __syncthreads();
    int n = blockIdx.x * 256 + tid;
    if (n >= N) return;
    const float x0 = x[n*3+0], x1 = x[n*3+1], x2 = x[n*3+2];
    float h[32];
#pragma unroll
    for (int k = 0; k < 32; ++k)
        h[k] = fmaxf(sW1[k*3+0]*x0 + sW1[k*3+1]*x1 + sW1[k*3+2]*x2, 0.0f);
    union { uint4 q[4]; unsigned u[16]; } st;
#pragma unroll
    for (int p = 0; p < 16; ++p) {
        float a0 = 0.f, a1 = 0.f;
#pragma unroll
        for (int k = 0; k < 32; ++k) {
            a0 += sW2[(2*p)  *32 + k] * h[k];
            a1 += sW2[(2*p+1)*32 + k] * h[k];
        }
        st.u[p] = pk2(a0, a1);
    }
    uint4* cp = (uint4*)(coorb + (size_t)n * 32);
#pragma unroll
    for (int w = 0; w < 4; ++w) cp[w] = st.q[w];
}

// ---------------- kernel 2: one-direction LSTM, 1 tile/wave, weights in LDS ----------------
template<int DIR>
__global__ __launch_bounds__(256, 4) void lstm_kernel(
    const float* __restrict__ edge_traj,
    const float* __restrict__ w_ih, const float* __restrict__ w_hh,
    const float* __restrict__ b_ih, const float* __restrict__ b_hh,
    unsigned* __restrict__ cbuf, int E)
{
    __shared__ unsigned lds_w[4096];
    const int tid = threadIdx.x;
    for (int i = tid; i < 512; i += 256) {
        const int m = i >> 6, ln = i & 63;
        const int le2 = ln & 15, lq2 = ln >> 4;
        const int row = 16*m + le2;
        const float s = (m == 4 || m == 5) ? LOG2E2 : -LOG2E;
        const float4 a = *(const float4*)(w_hh + row*32 + 4*lq2);
        const float4 b = *(const float4*)(w_hh + row*32 + 16 + 4*lq2);
        unsigned* wp = &lds_w[(size_t)i * 4];
        wp[0] = pk2(a.x*s, a.y*s); wp[1] = pk2(a.z*s, a.w*s);
        wp[2] = pk2(b.x*s, b.y*s); wp[3] = pk2(b.z*s, b.w*s);
        unsigned* xp = &lds_w[(size_t)(512 + i) * 4];
        if (lq2 == 0) {
            const float* p = w_ih + row * 6;
            xp[0] = pk2(p[0]*s, p[1]*s);
            xp[1] = pk2(p[2]*s, p[3]*s);
            xp[2] = pk2(p[4]*s, p[5]*s);
            xp[3] = pk2((b_ih[row] + b_hh[row])*s, 0.f);
        } else {
            xp[0] = 0u; xp[1] = 0u; xp[2] = 0u; xp[3] = 0u;
        }
    }
    __syncthreads();

    const int lane = tid & 63;
    const int wid  = tid >> 6;
    const int le   = lane & 15;
    const int lq   = lane >> 4;
    const bool l0  = (lq == 0);
    const unsigned lds_addr = (unsigned)(size_t)lds_w + (unsigned)lane * 16u;
    const f32x4 Z4 = {0.f, 0.f, 0.f, 0.f};

    const long tile = (long)blockIdx.x * 4 + wid;
    const long e0 = tile * 16;
    if (e0 >= E) return;
    const long er = e0 + le;
    const bool valid = er < E;
    const float* xb = edge_traj + (valid ? er : (E - 1)) * 48;

    U4 hf; hf.u[0]=hf.u[1]=hf.u[2]=hf.u[3]=0u;
    float cl[4]={0,0,0,0}, ch[4]={0,0,0,0};

#pragma unroll
    for (int t = 0; t < 8; ++t) {
        const int te = DIR ? (7 - t) : t;
        U4 xf;
        {
            const float* xp = xb + te * 6;
            const float2 a  = *(const float2*)xp;
            const float2 b2 = *(const float2*)(xp + 2);
            const float2 c2 = *(const float2*)(xp + 4);
            xf.u[0] = l0 ? pk2(a.x, a.y)   : 0u;
            xf.u[1] = l0 ? pk2(b2.x, b2.y) : 0u;
            xf.u[2] = l0 ? pk2(c2.x, c2.y) : 0u;
            xf.u[3] = l0 ? 0x3f80u         : 0u;
        }

        // ---- lo m-group {0,2,4,6}
        u32x4 f0,f1,f2,f3,f4,f5,f6,f7;
        LDS_RD8(lds_addr, f0,f1,f2,f3,f4,f5,f6,f7,
                "0","2048","4096","6144","8192","10240","12288","14336");
        f32x4 ai = MFMA(bc8(f4), xf.v, Z4, 0,0,0);
        f32x4 af = Z4, ao = Z4;
        if (t != 0) af = MFMA(bc8(f5), xf.v, Z4, 0,0,0);
        f32x4 ag = MFMA(bc8(f6), xf.v, Z4, 0,0,0);
        if (t != 7) ao = MFMA(bc8(f7), xf.v, Z4, 0,0,0);
        if (t > 0) {
            ai = MFMA(bc8(f0), hf.v, ai, 0,0,0);
            af = MFMA(bc8(f1), hf.v, af, 0,0,0);
            ag = MFMA(bc8(f2), hf.v, ag, 0,0,0);
            if (t != 7) ao = MFMA(bc8(f3), hf.v, ao, 0,0,0);
        }
        u32x4 g0,g1,g2,g3,g4,g5,g6,g7;
        LDS_RD8(lds_addr, g0,g1,g2,g3,g4,g5,g6,g7,
                "1024","3072","5120","7168","9216","11264","13312","15360");

        float hl[4], hh[4];
        if (t == 0)      gates4_first(ai, ag, ao, cl, hl);
        else if (t == 7) gates4_last(ai, af, ag, cl);
        else             gates4_mid(ai, af, ag, ao, cl, hl);

        f32x4 bi = MFMA(bc8(g4), xf.v, Z4, 0,0,0);
        f32x4 bf = Z4, bo = Z4;
        if (t != 0) bf = MFMA(bc8(g5), xf.v, Z4, 0,0,0);
        f32x4 bg = MFMA(bc8(g6), xf.v, Z4, 0,0,0);
        if (t != 7) bo = MFMA(bc8(g7), xf.v, Z4, 0,0,0);
        if (t > 0) {
            bi = MFMA(bc8(g0), hf.v, bi, 0,0,0);
            bf = MFMA(bc8(g1), hf.v, bf, 0,0,0);
            bg = MFMA(bc8(g2), hf.v, bg, 0,0,0);
            if (t != 7) bo = MFMA(bc8(g3), hf.v, bo, 0,0,0);
        }
        if (t == 0)      gates4_first(bi, bg, bo, ch, hh);
        else if (t == 7) gates4_last(bi, bf, bg, ch);
        else             gates4_mid(bi, bf, bg, bo, ch, hh);

        if (t < 7) {
            hf.u[0] = pk2(hl[0], hl[1]); hf.u[1] = pk2(hl[2], hl[3]);
            hf.u[2] = pk2(hh[0], hh[1]); hf.u[3] = pk2(hh[2], hh[3]);
        }
    }

    // c -> sigma-layout e-major bf16
    if (valid) {
        U4 cw;
        cw.u[0] = pk2(cl[0], cl[1]);
        cw.u[1] = pk2(cl[2], cl[3]);
        cw.u[2] = pk2(ch[0], ch[1]);
        cw.u[3] = pk2(ch[2], ch[3]);
        unsigned* dp = cbuf + er * 16 + lq * 4;
        if (DIR == 0) {
            *(uint4*)dp = *(uint4*)cw.u;
        } else {
            const uint4 f = *(const uint4*)dp;
            uint4 o;
            o.x = pk2(0.5f*(lo2f(f.x)+lo2f(cw.u[0])), 0.5f*(hi2f(f.x)+hi2f(cw.u[0])));
            o.y = pk2(0.5f*(lo2f(f.y)+lo2f(cw.u[1])), 0.5f*(hi2f(f.y)+hi2f(cw.u[1])));
            o.z = pk2(0.5f*(lo2f(f.z)+lo2f(cw.u[2])), 0.5f*(hi2f(f.z)+hi2f(cw.u[2])));
            o.w = pk2(0.5f*(lo2f(f.w)+lo2f(cw.u[3])), 0.5f*(hi2f(f.w)+hi2f(cw.u[3])));
            *(uint4*)dp = o;
        }
    }
}

// ---------------- kernel 3: message MLP, writes msg bf16 IN PLACE over tr rows ----------------
__global__ __launch_bounds__(256, 4) void msg_kernel(
    unsigned* trmsg,
    const float* __restrict__ nn2_w1, const float* __restrict__ nn2_w2,
    const int* __restrict__ edge_index,
    const unsigned short* __restrict__ coorb, int E)
{
    const int lane = threadIdx.x & 63;
    const int wid  = threadIdx.x >> 6;
    const int le   = lane & 15;
    const int lq   = lane >> 4;
    const f32x4 Z4 = {0.f, 0.f, 0.f, 0.f};

    bf16x8 w1a[2][3], w2a[2];
#pragma unroll
    for (int mm = 0; mm < 2; ++mm) {
        const int row = 16*mm + le;
        w1a[mm][0] = ldw8(nn2_w1 + row*96 +  8*lq);
        w1a[mm][1] = ldw8(nn2_w1 + row*96 + 32 + 8*lq);
        w1a[mm][2] = ldw8p(nn2_w1 + row*96 + 64, lq);
        w2a[mm]    = ldw8p(nn2_w2 + row*32, lq);
    }

    const long gw = (long)blockIdx.x * 4 + wid;
    for (int it = 0; it < MTPW; ++it) {
        const long tile = gw * MTPW + it;
        const long e0 = tile * 16;
        if (e0 >= E) break;
        const long e_raw = e0 + le;
        const bool valid = e_raw < E;
        const long ec = valid ? e_raw : (E - 1);

        U4 tf;
        if (valid) *(uint4*)tf.u = *(const uint4*)(trmsg + e_raw * 16 + lq * 4);
        else tf.u[0] = tf.u[1] = tf.u[2] = tf.u[3] = 0u;

        const int src = edge_index[ec];
        const int dst = edge_index[E + ec];
        U4 df, sf;
        {
            const uint4 dv = *(const uint4*)(coorb + (size_t)dst*32 + lq*8);
            const uint4 sv = *(const uint4*)(coorb + (size_t)src*32 + lq*8);
            df.u[0]=dv.x; df.u[1]=dv.y; df.u[2]=dv.z; df.u[3]=dv.w;
            sf.u[0]=sv.x; sf.u[1]=sv.y; sf.u[2]=sv.z; sf.u[3]=sv.w;
        }

        f32x4 h1[2];
#pragma unroll
        for (int mm = 0; mm < 2; ++mm) {
            f32x4 a = MFMA(w1a[mm][0], df.v, Z4, 0,0,0);
            a = MFMA(w1a[mm][1], sf.v, a, 0,0,0);
            a = MFMA(w1a[mm][2], tf.v, a, 0,0,0);
            h1[mm] = a;
        }
        U4 gf;
        gf.u[0] = pk2(fmaxf(h1[0][0],0.f), fmaxf(h1[0][1],0.f));
        gf.u[1] = pk2(fmaxf(h1[0][2],0.f), fmaxf(h1[0][3],0.f));
        gf.u[2] = pk2(fmaxf(h1[1][0],0.f), fmaxf(h1[1][1],0.f));
        gf.u[3] = pk2(fmaxf(h1[1][2],0.f), fmaxf(h1[1][3],0.f));

        const f32x4 o0 = MFMA(w2a[0], gf.v, Z4, 0,0,0);
        const f32x4 o1 = MFMA(w2a[1], gf.v, Z4, 0,0,0);
        if (valid) {
            U4 cw;
            cw.u[0] = pk2(o0[0], o0[1]);
            cw.u[1] = pk2(o0[2], o0[3]);
            cw.u[2] = pk2(o1[0], o1[1]);
            cw.u[3] = pk2(o1[2], o1[3]);
            *(uint4*)(trmsg + e_raw * 16 + lq * 4) = *(uint4*)cw.u;
        }
    }
}

// ---------------- CSR build ----------------
__global__ __launch_bounds__(256) void hist_kernel(
    const int* __restrict__ ei, int* __restrict__ cnt, int E)
{
    const int e = blockIdx.x*256 + threadIdx.x;
    if (e < E) atomicAdd(&cnt[ei[E + e]], 1);
}

__global__ __launch_bounds__(256) void scan1_kernel(
    const int* __restrict__ cnt, int* __restrict__ bsum, int N)
{
    __shared__ int sp[4];
    const int tid = threadIdx.x;
    const int n = blockIdx.x*256 + tid;
    int c = (n < N) ? cnt[n] : 0;
#pragma unroll
    for (int m = 1; m < 64; m <<= 1) c += __shfl_xor(c, m, 64);
    if ((tid & 63) == 0) sp[tid >> 6] = c;
    __syncthreads();
    if (tid == 0) bsum[blockIdx.x] = sp[0] + sp[1] + sp[2] + sp[3];
}

__global__ __launch_bounds__(512) void scan2_kernel(
    int* __restrict__ bsum, int* __restrict__ offs, int nblk, int E, int N)
{
    __shared__ int s[512];
    const int tid = threadIdx.x;
    const int v = (tid < nblk) ? bsum[tid] : 0;
    s[tid] = v;
    __syncthreads();
    for (int off = 1; off < 512; off <<= 1) {
        const int t = (tid >= off) ? s[tid - off] : 0;
        __syncthreads();
        s[tid] += t;
        __syncthreads();
    }
    if (tid < nblk) bsum[tid] = s[tid] - v;
    if (tid == 0) offs[N] = E;
}

__global__ __launch_bounds__(256) void scan3_kernel(
    const int* __restrict__ cnt, const int* __restrict__ bsum,
    int* __restrict__ offs, int* __restrict__ cursor, int N)
{
    __shared__ int s[256];
    const int tid = threadIdx.x;
    const int n = blockIdx.x*256 + tid;
    const int v = (n < N) ? cnt[n] : 0;
    s[tid] = v;
    __syncthreads();
    for (int off = 1; off < 256; off <<= 1) {
        const int t = (tid >= off) ? s[tid - off] : 0;
        __syncthreads();
        s[tid] += t;
        __syncthreads();
    }
    if (n < N) {
        const int o = bsum[blockIdx.x] + s[tid] - v;
        offs[n] = o;
        cursor[n] = o;
    }
}

__global__ __launch_bounds__(256) void fill_kernel(
    const int* __restrict__ ei, int* __restrict__ cursor,
    int* __restrict__ eidx, int E)
{
    const int e = blockIdx.x*256 + threadIdx.x;
    if (e < E) {
        const int p = atomicAdd(&cursor[ei[E + e]], 1);
        eidx[p] = e;
    }
}

// ---------------- gather: aggv[n][slot] = sum of msg rows of incoming edges ----------------
__global__ __launch_bounds__(256) void gather_kernel(
    const unsigned* __restrict__ msg, const int* __restrict__ offs,
    const int* __restrict__ eidx, float* __restrict__ aggv, int N)
{
    const int lane = threadIdx.x & 63;
    const int wid  = threadIdx.x >> 6;
    const int g  = lane >> 4;
    const int le = lane & 15;
    const int n = blockIdx.x*16 + wid*4 + g;
    if (n >= N) return;
    const int beg = offs[n], end = offs[n+1];
    float sx = 0.f, sy = 0.f;
    for (int i = beg; i < end; ++i) {
        const unsigned w = msg[(size_t)eidx[i]*16 + le];
        sx += lo2f(w); sy += hi2f(w);
    }
    *(float2*)(aggv + (size_t)n*32 + 2*le) = float2{sx, sy};
}

// ---------------- agg: partials[b][k] = sum_{n in block} relu(aggv[n]@nn_w1^T)[k] ----------------
__global__ __launch_bounds__(256) void agg_kernel(
    const float* __restrict__ aggv, const float* __restrict__ nn_w1,
    float* __restrict__ partials, int N)
{
    __shared__ float sW[1024];
    __shared__ float sP[4][32];
    const int tid = threadIdx.x;
    for (int i = tid; i < 1024; i += 256) {
        const int jj = i >> 5, s = i & 31, q = s >> 3, j = s & 7;
        const int col = (j < 4) ? (4*q + j) : (16 + 4*q + (j - 4));
        sW[i] = nn_w1[jj*32 + col];
    }
    __syncthreads();
    const int n = blockIdx.x*256 + tid;
    float h[32];
    if (n < N) {
        float a[32];
        const float4* ap = (const float4*)(aggv + (size_t)n*32);
#pragma unroll
        for (int k4 = 0; k4 < 8; ++k4) {
            const float4 v = ap[k4];
            a[k4*4]=v.x; a[k4*4+1]=v.y; a[k4*4+2]=v.z; a[k4*4+3]=v.w;
        }
#pragma unroll
        for (int jj = 0; jj < 32; ++jj) {
            float acc = 0.f;
#pragma unroll
            for (int k = 0; k < 32; ++k) acc += sW[jj*32+k]*a[k];
            h[jj] = fmaxf(acc, 0.f);
        }
    } else {
#pragma unroll
        for (int jj = 0; jj < 32; ++jj) h[jj] = 0.f;
    }
#pragma unroll
    for (int m = 1; m < 64; m <<= 1) {
#pragma unroll
        for (int k = 0; k < 32; ++k) h[k] += __shfl_xor(h[k], m, 64);
    }
    if ((tid & 63) == 0) {
#pragma unroll
        for (int k = 0; k < 32; ++k) sP[tid >> 6][k] = h[k];
    }
    __syncthreads();
    if (tid < 32)
        partials[(size_t)blockIdx.x * 32 + tid]
            = sP[0][tid] + sP[1][tid] + sP[2][tid] + sP[3][tid];
}

// ---------------- final: s32 = sum(partials); out = nn_w2 @ s32 ----------------
__global__ __launch_bounds__(256) void reduce_kernel(
    const float* __restrict__ partials, const float* __restrict__ nn_w2,
    float* __restrict__ out, int nblk)
{
    __shared__ float sR[8][32];
    __shared__ float sS[32];
    const int tid = threadIdx.x;
    const int col = tid & 31;
    const int row = tid >> 5;
    float s = 0.f;
    for (int i = row; i < nblk; i += 8) s += partials[(size_t)i*32 + col];
    sR[row][col] = s;
    __syncthreads();
    if (row == 0) {
        float t = 0.f;
#pragma unroll
        for (int r = 0; r < 8; ++r) t += sR[r][col];
        sS[col] = t;
    }
    __syncthreads();
    if (tid < 64) {
        float acc = 0.f;
#pragma unroll
        for (int k = 0; k < 32; ++k) acc += nn_w2[tid*32+k] * sS[k];
        out[tid] = acc;
    }
}

extern "C" void kernel_launch(void* const* d_in, const int* in_sizes, int n_in,
                              void* d_out, int out_size, void* d_ws, size_t ws_size,
                              hipStream_t stream)
{
    const float* x         = (const float*)d_in[0];
    const float* edge_traj = (const float*)d_in[1];
    const float* w_ih_f    = (const float*)d_in[2];
    const float* w_hh_f    = (const float*)d_in[3];
    const float* b_ih_f    = (const float*)d_in[4];
    const float* b_hh_f    = (const float*)d_in[5];
    const float* w_ih_b    = (const float*)d_in[6];
    const float* w_hh_b    = (const float*)d_in[7];
    const float* b_ih_b    = (const float*)d_in[8];
    const float* b_hh_b    = (const float*)d_in[9];
    const float* coor_w1   = (const float*)d_in[10];
    const float* coor_w2   = (const float*)d_in[11];
    const float* nn2_w1    = (const float*)d_in[12];
    const float* nn2_w2    = (const float*)d_in[13];
    const float* nn_w1     = (const float*)d_in[14];
    const float* nn_w2     = (const float*)d_in[15];
    const int* edge_index  = (const int*)d_in[16];
    const int N = in_sizes[0] / 3;
    const int E = in_sizes[16] / 2;
    const int nblk = (N + 255) / 256;

    float* aggv = (float*)d_ws;                                   // N*32 f32
    float* partials = aggv + (size_t)N * 32;                      // nblk*32 f32
    unsigned short* coorb = (unsigned short*)(partials + (size_t)nblk * 32); // N*32 bf16
    unsigned* cbuf = (unsigned*)(coorb + (size_t)N * 32);         // E*16 u32 (tr -> msg)
    int* cnt    = (int*)(cbuf + (size_t)E * 16);                  // N
    int* offs   = cnt + N;                                        // N+1
    int* cursor = offs + N + 1;                                   // N
    int* eidx   = cursor + N;                                     // E
    int* bsum   = eidx + E;                                       // nblk

    (void)hipMemsetAsync(cnt, 0, (size_t)N * sizeof(int), stream);

    coor_kernel<<<nblk, 256, 0, stream>>>(x, coor_w1, coor_w2, coorb, N);

    const long tiles   = ((long)E + 15) / 16;
    const int  lblocks = (int)((tiles + 3) / 4);
    lstm_kernel<0><<<lblocks, 256, 0, stream>>>(edge_traj,
        w_ih_f, w_hh_f, b_ih_f, b_hh_f, cbuf, E);
    lstm_kernel<1><<<lblocks, 256, 0, stream>>>(edge_traj,
        w_ih_b, w_hh_b, b_ih_b, b_hh_b, cbuf, E);

    const int eblk = (E + 255) / 256;
    hist_kernel<<<eblk, 256, 0, stream>>>(edge_index, cnt, E);
    scan1_kernel<<<nblk, 256, 0, stream>>>(cnt, bsum, N);
    scan2_kernel<<<1, 512, 0, stream>>>(bsum, offs, nblk, E, N);
    scan3_kernel<<<nblk, 256, 0, stream>>>(cnt, bsum, offs, cursor, N);
    fill_kernel<<<eblk, 256, 0, stream>>>(edge_index, cursor, eidx, E);

    const int mblocks = (int)((tiles + 4*MTPW - 1) / (4*MTPW));
    msg_kernel<<<mblocks, 256, 0, stream>>>(cbuf, nn2_w1, nn2_w2,
        edge_index, coorb, E);

    gather_kernel<<<(N + 15)/16, 256, 0, stream>>>(cbuf, offs, eidx, aggv, N);
    agg_kernel<<<nblk, 256, 0, stream>>>(aggv, nn_w1, partials, N);
    reduce_kernel<<<1, 256, 0, stream>>>(partials, nn_w2, (float*)d_out, nblk);
}